// Round 9
// baseline (462.432 us; speedup 1.0000x reference)
//
#include <hip/hip_runtime.h>
#include <hip/hip_bf16.h>
#include <math.h>

#define N_NODES 100000
#define IN_F 256
#define HID 128
#define NCLS 40
#define CH 2048          // partition chunks
#define CSZ 832          // edges per chunk (64-aligned, CH*CSZ >= E)

typedef __attribute__((ext_vector_type(8))) short short8;
typedef __attribute__((ext_vector_type(4))) float f32x4;

__device__ __forceinline__ short f2bf(float f){
  union { float f; unsigned u; } x; x.f = f;
  unsigned r = (x.u + 0x7fffu + ((x.u >> 16) & 1u)) >> 16;
  return (short)r;
}
__device__ __forceinline__ float bf2f(unsigned short u){
  union { unsigned u; float f; } x; x.u = ((unsigned)u) << 16;
  return x.f;
}

// ---------------- weight pre-pack: f32 -> bf16 MFMA B-frag images ----------------
// img layout: [0,32768) pre | [32768,65536) sage L0 | [65536,98304) sage L1 |
//             [98304,104448) post. Each image is the flat [ct][kb][64][8] frag tile.
__global__ __launch_bounds__(256) void k_wprep(
    const float* __restrict__ Wpre, const float* __restrict__ Wl0,
    const float* __restrict__ Wr0,  const float* __restrict__ Wl1,
    const float* __restrict__ Wr1,  const float* __restrict__ Wpost,
    unsigned short* __restrict__ img)
{
  const int g = blockIdx.x*256 + threadIdx.x;   // one short8 per thread
  if(g >= 13056) return;
  const int base = g*8;
  unsigned short v[8];
  if(base < 98304){
    const int which = base >> 15;               // 0=pre, 1=L0, 2=L1
    const int idx = base & 32767;
    const int l = (idx >> 3) & 63, kb = (idx >> 9) & 7, ct = idx >> 12;
    const int col = ct*16 + (l & 15);
    const float* Wsrc; int kbase;
    if(which == 0){ Wsrc = Wpre; kbase = kb*32 + (l>>4)*8; }
    else{
      Wsrc = (which==1) ? ((kb<4) ? Wl0 : Wr0) : ((kb<4) ? Wl1 : Wr1);
      kbase = (kb&3)*32 + (l>>4)*8;
    }
    #pragma unroll
    for(int j = 0; j < 8; j++) v[j] = (unsigned short)f2bf(Wsrc[(size_t)(kbase+j)*HID + col]);
  } else {
    const int idx = base - 98304;               // post image [3][4][64][8]
    const int l = (idx >> 3) & 63, kb = (idx >> 9) & 3, ct = idx >> 11;
    const int col = ct*16 + (l & 15);
    const int kbase = kb*32 + (l>>4)*8;
    #pragma unroll
    for(int j = 0; j < 8; j++)
      v[j] = (col < NCLS) ? (unsigned short)f2bf(Wpost[(size_t)(kbase+j)*NCLS + col]) : 0;
  }
  *reinterpret_cast<short8*>(img + base) = *reinterpret_cast<const short8*>(v);
}

// ---------------- CSR build: deterministic 8-way partition ----------------
__global__ void k_zero(int* p, int n){
  int i = blockIdx.x*blockDim.x + threadIdx.x;
  if(i < n) p[i] = 0;
}

// One wave per chunk: count this chunk's edges per color (no atomics).
__global__ __launch_bounds__(256) void k_pcnt(const int* __restrict__ dst, int e,
                                              int* __restrict__ cnt){
  const int w = blockIdx.x*4 + (threadIdx.x >> 6);
  const int lane = threadIdx.x & 63;
  const int s0 = w*CSZ;
  const int s1 = min(s0 + CSZ, e);
  int c0=0,c1=0,c2=0,c3=0,c4=0,c5=0,c6=0,c7=0;
  for(int i = s0 + lane; i < s1; i += 64){
    const int col = (unsigned)__builtin_nontemporal_load(dst + i) / (N_NODES/8);
    c0 += (col==0); c1 += (col==1); c2 += (col==2); c3 += (col==3);
    c4 += (col==4); c5 += (col==5); c6 += (col==6); c7 += (col==7);
  }
  #pragma unroll
  for(int o = 32; o > 0; o >>= 1){
    c0 += __shfl_xor(c0,o); c1 += __shfl_xor(c1,o); c2 += __shfl_xor(c2,o); c3 += __shfl_xor(c3,o);
    c4 += __shfl_xor(c4,o); c5 += __shfl_xor(c5,o); c6 += __shfl_xor(c6,o); c7 += __shfl_xor(c7,o);
  }
  int outv = c0;
  if(lane==1) outv=c1; if(lane==2) outv=c2; if(lane==3) outv=c3;
  if(lane==4) outv=c4; if(lane==5) outv=c5; if(lane==6) outv=c6; if(lane==7) outv=c7;
  if(lane < 8) cnt[lane*CH + w] = outv;   // color-major layout
}

// Exclusive scan of the 8*CH count matrix (color-major) -> per-(color,chunk) base.
__global__ __launch_bounds__(1024) void k_pscan(const int* __restrict__ cnt,
                                                int* __restrict__ base){
  __shared__ int s[1024];
  const int t = threadIdx.x;
  int v[16]; int sum = 0;
  #pragma unroll
  for(int j = 0; j < 16; j++){ v[j] = cnt[t*16 + j]; int x = sum; sum += v[j]; v[j] = x; }
  s[t] = sum; __syncthreads();
  for(int d = 1; d < 1024; d <<= 1){
    int add = (t >= d) ? s[t-d] : 0;
    __syncthreads();
    s[t] += add;
    __syncthreads();
  }
  const int bofs = (t > 0) ? s[t-1] : 0;
  #pragma unroll
  for(int j = 0; j < 16; j++) base[t*16 + j] = bofs + v[j];
  if(t == 1023) base[8*CH] = s[1023];     // total = E
}

// Same wave mapping: append (dst,src) to per-color contiguous planes via
// ballot ranks. Coalesced writes, zero atomics, deterministic.
__global__ __launch_bounds__(256) void k_pplace(const int* __restrict__ src,
                                                const int* __restrict__ dst, int e,
                                                const int* __restrict__ base,
                                                int* __restrict__ pd, int* __restrict__ ps){
  const int w = blockIdx.x*4 + (threadIdx.x >> 6);
  const int lane = threadIdx.x & 63;
  const int s0 = w*CSZ;
  const int s1 = min(s0 + CSZ, e);
  int b[8];
  #pragma unroll
  for(int k = 0; k < 8; k++) b[k] = base[k*CH + w];
  const unsigned long long ltmask = (lane==63) ? ~0ull>>1 : ((1ull<<lane)-1);
  for(int i0 = s0; i0 < s1; i0 += 64){
    const int i = i0 + lane;
    const bool val = i < s1;
    const int d = val ? __builtin_nontemporal_load(dst + i) : -1;
    const int sv = val ? __builtin_nontemporal_load(src + i) : 0;
    const int col = val ? (int)((unsigned)d / (N_NODES/8)) : -1;
    #pragma unroll
    for(int k = 0; k < 8; k++){
      const unsigned long long m = __ballot(col == k);
      if(col == k){
        const int rank = __popcll(m & ltmask);
        pd[b[k] + rank] = d;
        ps[b[k] + rank] = sv;
      }
      b[k] += __popcll(m);
    }
  }
}

#define SCAN_BLK 512
__global__ void k_scanA(const int* __restrict__ counts, int* __restrict__ offs,
                        int* __restrict__ partials, int n){
  __shared__ int s[SCAN_BLK];
  const int t = threadIdx.x;
  const int i = blockIdx.x*SCAN_BLK + t;
  int v = (i < n) ? counts[i] : 0;
  s[t] = v; __syncthreads();
  for(int d = 1; d < SCAN_BLK; d <<= 1){
    int add = (t >= d) ? s[t-d] : 0;
    __syncthreads();
    s[t] += add;
    __syncthreads();
  }
  if(i < n) offs[i] = s[t] - v;
  if(t == SCAN_BLK-1) partials[blockIdx.x] = s[t];
}

__global__ void k_scanB(int* partials, int n){
  __shared__ int s[256];
  const int t = threadIdx.x;
  int v = (t < n) ? partials[t] : 0;
  s[t] = v; __syncthreads();
  for(int d = 1; d < 256; d <<= 1){
    int add = (t >= d) ? s[t-d] : 0;
    __syncthreads();
    s[t] += add;
    __syncthreads();
  }
  if(t < n) partials[t] = s[t] - v;
}

__global__ void k_scanC(int* __restrict__ offs, const int* __restrict__ partials,
                        int* __restrict__ cursor, int n){
  int i = blockIdx.x*blockDim.x + threadIdx.x;
  if(i < n){
    int v = offs[i] + partials[blockIdx.x];
    offs[i] = v;
    cursor[i] = v;
  }
}

// Colored count from the contiguous color partition (reads 1/8 each).
__global__ __launch_bounds__(256) void k_count2(const int* __restrict__ pd,
                                                const int* __restrict__ base,
                                                int* __restrict__ counts){
  const int color = blockIdx.x & 7;
  const int c0 = base[color*CH], c1 = base[(color+1)*CH];
  const int stride = (gridDim.x >> 3) * 256;
  for(int i = c0 + (blockIdx.x >> 3)*256 + threadIdx.x; i < c1; i += stride)
    atomicAdd(&counts[__builtin_nontemporal_load(pd + i)], 1);
}

// Colored scatter; color = blockIdx>>8 gives TEMPORAL clustering: all ~256
// consecutive blocks (across all XCDs) work one color's 800KB esrc window at a
// time, so each output line's ~16 slots fill while the line is cache-resident.
__global__ __launch_bounds__(256) void k_scatter2(const int* __restrict__ pd,
                                                  const int* __restrict__ ps,
                                                  const int* __restrict__ base,
                                                  int* __restrict__ cursor,
                                                  int* __restrict__ esrc){
  const int color = blockIdx.x >> 8;            // 2048 blocks -> 8 colors, consecutive
  const int sub   = blockIdx.x & 255;
  const int c0 = base[color*CH], c1 = base[(color+1)*CH];
  const int stride = 256 * 256;
  for(int i = c0 + sub*256 + threadIdx.x; i < c1; i += stride){
    const int d = __builtin_nontemporal_load(pd + i);
    const int s = __builtin_nontemporal_load(ps + i);
    const int pos = atomicAdd(&cursor[d], 1);
    esrc[pos] = s;
  }
}

// ---------------- pre GEMM: h0 = x @ W_pre + b_pre  (f32 in, bf16 out) ----------------
// Proven round-5 config; staging now a coalesced short8 copy of the prepacked image.
__global__ __launch_bounds__(256) void k_gemm_pre(
    const float* __restrict__ x, const unsigned short* __restrict__ wimg,
    const float* __restrict__ b, unsigned short* __restrict__ out)
{
  __shared__ short wlds[8*8*64*8];   // flat [ct][kb][lane][j], 64 KiB
  const int t = threadIdx.x;
  {
    short8* dstp = reinterpret_cast<short8*>(wlds);
    const short8* srcp = reinterpret_cast<const short8*>(wimg);
    #pragma unroll
    for(int i = 0; i < 16; i++) dstp[t + i*256] = srcp[t + i*256];
  }
  __syncthreads();
  const int wave = t >> 6, lane = t & 63;
  const int r_in = lane & 15, kg = lane >> 4;
  for(int tile = blockIdx.x*4 + wave; tile < N_NODES/16; tile += gridDim.x*4){
    const int row0 = tile*16;
    const float* xp = x + (size_t)(row0 + r_in)*IN_F + kg*8;
    float4 xa[8], xb[8];
    #pragma unroll
    for(int kb = 0; kb < 8; kb++){
      xa[kb] = *reinterpret_cast<const float4*>(xp + kb*32);
      xb[kb] = *reinterpret_cast<const float4*>(xp + kb*32 + 4);
    }
    f32x4 acc[8];
    #pragma unroll
    for(int ct = 0; ct < 8; ct++) acc[ct] = (f32x4){0.f,0.f,0.f,0.f};
    #pragma unroll
    for(int kb = 0; kb < 8; kb++){
      short8 a;
      a[0]=f2bf(xa[kb].x); a[1]=f2bf(xa[kb].y); a[2]=f2bf(xa[kb].z); a[3]=f2bf(xa[kb].w);
      a[4]=f2bf(xb[kb].x); a[5]=f2bf(xb[kb].y); a[6]=f2bf(xb[kb].z); a[7]=f2bf(xb[kb].w);
      #pragma unroll
      for(int ct = 0; ct < 8; ct++){
        short8 bb = *reinterpret_cast<const short8*>(&wlds[((ct*8+kb)*64+lane)*8]);
        acc[ct] = __builtin_amdgcn_mfma_f32_16x16x32_bf16(a, bb, acc[ct], 0, 0, 0);
      }
    }
    #pragma unroll
    for(int ct = 0; ct < 8; ct++){
      const int col = ct*16 + r_in;
      const float bias = b[col];
      #pragma unroll
      for(int i = 0; i < 4; i++){
        const int row = row0 + kg*4 + i;
        out[(size_t)row*HID + col] = (unsigned short)f2bf(acc[ct][i] + bias);
      }
    }
  }
}

// ------- sage GEMM: out = relu(mean @ Wl + bl + h @ Wr)  (bf16 in/out) -------
// r8 body; staging swapped to prepacked-image copy.
__global__ __launch_bounds__(256) void k_gemm_sage(
    const unsigned short* __restrict__ mean, const unsigned short* __restrict__ h,
    const unsigned short* __restrict__ wimg, const float* __restrict__ bl,
    unsigned short* __restrict__ out)
{
  __shared__ short wlds[8*8*64*8];   // flat; kb 0..3 -> Wl, 4..7 -> Wr
  const int t = threadIdx.x;
  {
    short8* dstp = reinterpret_cast<short8*>(wlds);
    const short8* srcp = reinterpret_cast<const short8*>(wimg);
    #pragma unroll
    for(int i = 0; i < 16; i++) dstp[t + i*256] = srcp[t + i*256];
  }
  __syncthreads();
  const int wave = t >> 6, lane = t & 63;
  const int r_in = lane & 15, kg = lane >> 4;
  for(int tile = blockIdx.x*4 + wave; tile < N_NODES/16; tile += gridDim.x*4){
    const int row0 = tile*16;
    f32x4 acc[8];
    #pragma unroll
    for(int ct = 0; ct < 8; ct++) acc[ct] = (f32x4){0.f,0.f,0.f,0.f};
    #pragma unroll
    for(int kb = 0; kb < 8; kb++){
      const unsigned short* in = (kb < 4) ? mean : h;
      const int koff = (kb & 3)*32 + kg*8;
      short8 a = *reinterpret_cast<const short8*>(in + (size_t)(row0 + r_in)*HID + koff);
      #pragma unroll
      for(int ct = 0; ct < 8; ct++){
        short8 bb = *reinterpret_cast<const short8*>(&wlds[((ct*8+kb)*64+lane)*8]);
        acc[ct] = __builtin_amdgcn_mfma_f32_16x16x32_bf16(a, bb, acc[ct], 0, 0, 0);
      }
    }
    #pragma unroll
    for(int ct = 0; ct < 8; ct++){
      const int col = ct*16 + r_in;
      const float bias = bl[col];
      #pragma unroll
      for(int i = 0; i < 4; i++){
        const int row = row0 + kg*4 + i;
        float v = fmaxf(acc[ct][i] + bias, 0.f);
        out[(size_t)row*HID + col] = (unsigned short)f2bf(v);
      }
    }
  }
}

// ---------------- CSR mean aggregation (bf16 h -> bf16 mean) ----------------
__global__ __launch_bounds__(256) void k_aggregate(
    const unsigned short* __restrict__ h, const int* __restrict__ offs,
    const int* __restrict__ counts, const int* __restrict__ esrc,
    unsigned short* __restrict__ mean)
{
  const int node = blockIdx.x*4 + (threadIdx.x >> 6);
  const int lane = threadIdx.x & 63;
  if(node >= N_NODES) return;
  const int beg = offs[node];
  const int deg = counts[node];
  const unsigned* hp = (const unsigned*)h;
  float a0 = 0.f, a1 = 0.f;
  for(int base = 0; base < deg; base += 64){
    const int rem = deg - base;
    const int cnt = rem < 64 ? rem : 64;
    const int myi = (lane < cnt) ? esrc[beg + base + lane] : 0;   // coalesced
    int e = 0;
    for(; e + 8 <= cnt; e += 8){
      unsigned v[8];
      #pragma unroll
      for(int u = 0; u < 8; u++){
        const int s = __builtin_amdgcn_readlane(myi, e + u);
        v[u] = hp[(size_t)s*64 + lane];
      }
      #pragma unroll
      for(int u = 0; u < 8; u++){
        a0 += bf2f((unsigned short)(v[u] & 0xffffu));
        a1 += bf2f((unsigned short)(v[u] >> 16));
      }
    }
    for(; e < cnt; e++){
      const int s = __builtin_amdgcn_readlane(myi, e);
      const unsigned vv = hp[(size_t)s*64 + lane];
      a0 += bf2f((unsigned short)(vv & 0xffffu));
      a1 += bf2f((unsigned short)(vv >> 16));
    }
  }
  const float inv = (deg > 0) ? (1.0f/(float)deg) : 0.f;
  a0 *= inv; a1 *= inv;
  unsigned o = ((unsigned)(unsigned short)f2bf(a1) << 16) | (unsigned)(unsigned short)f2bf(a0);
  ((unsigned*)mean)[(size_t)node*64 + lane] = o;
}

// ---------------- post: log_softmax(h @ W_post + b_post), MFMA ----------------
__global__ __launch_bounds__(256) void k_post(
    const unsigned short* __restrict__ h, const unsigned short* __restrict__ wimg,
    const float* __restrict__ b, float* __restrict__ out)
{
  __shared__ short wlds[3*4*64*8];   // flat [ct][kb][lane][j], 12 KiB
  __shared__ float bias_s[48];
  const int t = threadIdx.x;
  {
    short8* dstp = reinterpret_cast<short8*>(wlds);
    const short8* srcp = reinterpret_cast<const short8*>(wimg);
    for(int i = t; i < 768; i += 256) dstp[i] = srcp[i];
  }
  if(t < 48) bias_s[t] = (t < NCLS) ? b[t] : -1e30f;
  __syncthreads();
  const int wave = t >> 6, lane = t & 63;
  const int r_in = lane & 15, kg = lane >> 4;
  for(int tile = blockIdx.x*4 + wave; tile < N_NODES/16; tile += gridDim.x*4){
    const int row0 = tile*16;
    f32x4 acc[3];
    #pragma unroll
    for(int ct = 0; ct < 3; ct++) acc[ct] = (f32x4){0.f,0.f,0.f,0.f};
    #pragma unroll
    for(int kb = 0; kb < 4; kb++){
      short8 a = *reinterpret_cast<const short8*>(h + (size_t)(row0 + r_in)*HID + kb*32 + kg*8);
      #pragma unroll
      for(int ct = 0; ct < 3; ct++){
        short8 bb = *reinterpret_cast<const short8*>(&wlds[((ct*4+kb)*64+lane)*8]);
        acc[ct] = __builtin_amdgcn_mfma_f32_16x16x32_bf16(a, bb, acc[ct], 0, 0, 0);
      }
    }
    #pragma unroll
    for(int i = 0; i < 4; i++){
      float v0 = acc[0][i] + bias_s[r_in];
      float v1 = acc[1][i] + bias_s[16 + r_in];
      float v2 = acc[2][i] + bias_s[32 + r_in];
      float m = fmaxf(fmaxf(v0, v1), v2);
      #pragma unroll
      for(int o = 8; o > 0; o >>= 1) m = fmaxf(m, __shfl_xor(m, o));
      float s = expf(v0 - m) + expf(v1 - m) + expf(v2 - m);
      #pragma unroll
      for(int o = 8; o > 0; o >>= 1) s += __shfl_xor(s, o);
      const float ls = m + logf(s);
      const int row = row0 + kg*4 + i;
      float* op = out + (size_t)row*NCLS;
      op[r_in] = v0 - ls;
      op[16 + r_in] = v1 - ls;
      if(r_in < 8) op[32 + r_in] = v2 - ls;
    }
  }
}

extern "C" void kernel_launch(void* const* d_in, const int* in_sizes, int n_in,
                              void* d_out, int out_size, void* d_ws, size_t ws_size,
                              hipStream_t stream)
{
  const float* x      = (const float*)d_in[0];
  const int*   ei     = (const int*)  d_in[1];
  const float* W_pre  = (const float*)d_in[2];
  const float* b_pre  = (const float*)d_in[3];
  const float* Wl0    = (const float*)d_in[4];
  const float* bl0    = (const float*)d_in[5];
  const float* Wr0    = (const float*)d_in[6];
  const float* Wl1    = (const float*)d_in[7];
  const float* bl1    = (const float*)d_in[8];
  const float* Wr1    = (const float*)d_in[9];
  const float* W_post = (const float*)d_in[10];
  const float* b_post = (const float*)d_in[11];
  float* out = (float*)d_out;

  const int E = in_sizes[1] / 2;
  const int* src = ei;
  const int* dst = ei + E;

  char* ws = (char*)d_ws;
  size_t off = 0;
  auto alloc = [&](size_t bytes)->void*{
    void* p = ws + off;
    off += (bytes + 255) & ~(size_t)255;
    return p;
  };
  unsigned short* hA = (unsigned short*)alloc((size_t)N_NODES*HID*2);
  unsigned short* hB = (unsigned short*)alloc((size_t)N_NODES*HID*2);
  unsigned short* hM = (unsigned short*)alloc((size_t)N_NODES*HID*2);
  int* counts   = (int*)alloc((size_t)N_NODES*4);
  int* offs     = (int*)alloc((size_t)N_NODES*4);
  int* cursor   = (int*)alloc((size_t)N_NODES*4);
  int* esrc     = (int*)alloc((size_t)E*4);
  int* partials = (int*)alloc(1024);
  unsigned short* wimg = (unsigned short*)alloc(104448*2);   // prepacked weights

  // Partition scratch aliased into buffers first written AFTER the CSR build.
  int* pd   = (int*)hM;            // CH*CSZ ints
  int* ps   = pd + CH*CSZ;         // CH*CSZ ints
  int* cnt  = (int*)hB;            // 8*CH ints
  int* base = cnt + 8*CH;          // 8*CH+1 ints

  // ---- weight pre-pack (one-time per launch) ----
  k_wprep<<<51, 256, 0, stream>>>(W_pre, Wl0, Wr0, Wl1, Wr1, W_post, wimg);

  // ---- CSR build: deterministic partition -> colored count/scatter ----
  k_zero<<<(N_NODES+255)/256, 256, 0, stream>>>(counts, N_NODES);
  k_pcnt<<<CH/4, 256, 0, stream>>>(dst, E, cnt);
  k_pscan<<<1, 1024, 0, stream>>>(cnt, base);
  k_pplace<<<CH/4, 256, 0, stream>>>(src, dst, E, base, pd, ps);
  k_count2<<<2048, 256, 0, stream>>>(pd, base, counts);
  const int nb = (N_NODES + SCAN_BLK - 1) / SCAN_BLK;       // 196
  k_scanA<<<nb, SCAN_BLK, 0, stream>>>(counts, offs, partials, N_NODES);
  k_scanB<<<1, 256, 0, stream>>>(partials, nb);
  k_scanC<<<nb, SCAN_BLK, 0, stream>>>(offs, partials, cursor, N_NODES);
  k_scatter2<<<2048, 256, 0, stream>>>(pd, ps, base, cursor, esrc);

  // ---- pre linear ----
  k_gemm_pre<<<512, 256, 0, stream>>>(x, wimg, b_pre, hA);

  // ---- SAGE layer 0 ----
  k_aggregate<<<N_NODES/4, 256, 0, stream>>>(hA, offs, counts, esrc, hM);
  k_gemm_sage<<<1563, 256, 0, stream>>>(hM, hA, wimg + 32768, bl0, hB);

  // ---- SAGE layer 1 ----
  k_aggregate<<<N_NODES/4, 256, 0, stream>>>(hB, offs, counts, esrc, hM);
  k_gemm_sage<<<1563, 256, 0, stream>>>(hM, hB, wimg + 65536, bl1, hA);

  // ---- post linear + log_softmax (MFMA) ----
  k_post<<<1563, 256, 0, stream>>>(hA, wimg + 98304, b_post, out);
}

// Round 10
// 418.672 us; speedup vs baseline: 1.1045x; 1.1045x over previous
//
#include <hip/hip_runtime.h>
#include <hip/hip_bf16.h>
#include <math.h>

#define N_NODES 100000
#define IN_F 256
#define HID 128
#define NCLS 40

#define NB 782           // buckets of BN consecutive nodes (dst>>7)
#define BN 128
#define NC 49            // chunks of CSZ2 edges
#define CSZ2 32768
#define CAP 4096         // max staged edges per bucket (avg ~2053)

typedef __attribute__((ext_vector_type(8))) short short8;
typedef __attribute__((ext_vector_type(4))) float f32x4;

__device__ __forceinline__ short f2bf(float f){
  union { float f; unsigned u; } x; x.f = f;
  unsigned r = (x.u + 0x7fffu + ((x.u >> 16) & 1u)) >> 16;
  return (short)r;
}
__device__ __forceinline__ float bf2f(unsigned short u){
  union { unsigned u; float f; } x; x.u = ((unsigned)u) << 16;
  return x.f;
}

// ---------------- weight pre-pack: f32 -> bf16 MFMA B-frag images ----------------
__global__ __launch_bounds__(256) void k_wprep(
    const float* __restrict__ Wpre, const float* __restrict__ Wl0,
    const float* __restrict__ Wr0,  const float* __restrict__ Wl1,
    const float* __restrict__ Wr1,  const float* __restrict__ Wpost,
    unsigned short* __restrict__ img)
{
  const int g = blockIdx.x*256 + threadIdx.x;   // one short8 per thread
  if(g >= 13056) return;
  const int base = g*8;
  unsigned short v[8];
  if(base < 98304){
    const int which = base >> 15;               // 0=pre, 1=L0, 2=L1
    const int idx = base & 32767;
    const int l = (idx >> 3) & 63, kb = (idx >> 9) & 7, ct = idx >> 12;
    const int col = ct*16 + (l & 15);
    const float* Wsrc; int kbase;
    if(which == 0){ Wsrc = Wpre; kbase = kb*32 + (l>>4)*8; }
    else{
      Wsrc = (which==1) ? ((kb<4) ? Wl0 : Wr0) : ((kb<4) ? Wl1 : Wr1);
      kbase = (kb&3)*32 + (l>>4)*8;
    }
    #pragma unroll
    for(int j = 0; j < 8; j++) v[j] = (unsigned short)f2bf(Wsrc[(size_t)(kbase+j)*HID + col]);
  } else {
    const int idx = base - 98304;               // post image [3][4][64][8]
    const int l = (idx >> 3) & 63, kb = (idx >> 9) & 3, ct = idx >> 11;
    const int col = ct*16 + (l & 15);
    const int kbase = kb*32 + (l>>4)*8;
    #pragma unroll
    for(int j = 0; j < 8; j++)
      v[j] = (col < NCLS) ? (unsigned short)f2bf(Wpost[(size_t)(kbase+j)*NCLS + col]) : 0;
  }
  *reinterpret_cast<short8*>(img + base) = *reinterpret_cast<const short8*>(v);
}

// ---------------- bucketed edge partition (replaces CSR build) ----------------
// Per-chunk bucket histogram.
__global__ __launch_bounds__(256) void k_hist(const int* __restrict__ dst, int E,
                                              int* __restrict__ cnt){
  __shared__ int hist[NB];
  const int c = blockIdx.x;
  for(int i = threadIdx.x; i < NB; i += 256) hist[i] = 0;
  __syncthreads();
  const int s0 = c*CSZ2, s1 = min(s0 + CSZ2, E);
  for(int i = s0 + threadIdx.x; i < s1; i += 256)
    atomicAdd(&hist[(unsigned)__builtin_nontemporal_load(dst + i) >> 7], 1);
  __syncthreads();
  for(int i = threadIdx.x; i < NB; i += 256) cnt[c*NB + i] = hist[i];   // [c][b]
}

// base[c][b] = global start of (bucket b, chunk c) run. base[0][b] = bucket start.
__global__ __launch_bounds__(1024) void k_bscan(const int* __restrict__ cnt,
                                                int* __restrict__ base){
  __shared__ int s[1024];
  const int t = threadIdx.x;
  int tot = 0;
  if(t < NB){
    for(int c = 0; c < NC; c++){
      const int v = cnt[c*NB + t];
      base[c*NB + t] = tot;          // within-bucket exclusive
      tot += v;
    }
  }
  s[t] = tot; __syncthreads();
  for(int d = 1; d < 1024; d <<= 1){
    int add = (t >= d) ? s[t-d] : 0;
    __syncthreads();
    s[t] += add;
    __syncthreads();
  }
  const int bb = (t > 0) ? s[t-1] : 0;
  if(t < NB)
    for(int c = 0; c < NC; c++) base[c*NB + t] += bb;
}

// Place packed edges ((dst&127)<<17 | src) into bucket-contiguous pk via LDS
// cursors. Each (bucket,chunk) run (~42 ints) is written contiguously by one
// block; chunk->block mapping groups consecutive chunks on one XCD so dirty
// lines stay in one L2 (the r6-r9 lesson: one line, one XCD, one lifetime).
__global__ __launch_bounds__(256) void k_place(const int* __restrict__ src,
                                               const int* __restrict__ dst, int E,
                                               const int* __restrict__ base,
                                               int* __restrict__ pk){
  const int g = blockIdx.x;            // 56 blocks: 8 XCD groups x 7
  const int c = (g & 7)*7 + (g >> 3);
  if(c >= NC) return;
  __shared__ int cur[NB];
  for(int i = threadIdx.x; i < NB; i += 256) cur[i] = base[c*NB + i];
  __syncthreads();
  const int s0 = c*CSZ2, s1 = min(s0 + CSZ2, E);
  for(int i = s0 + threadIdx.x; i < s1; i += 256){
    const int d  = __builtin_nontemporal_load(dst + i);
    const int sv = __builtin_nontemporal_load(src + i);
    const int pos = atomicAdd(&cur[(unsigned)d >> 7], 1);
    pk[pos] = ((d & 127) << 17) | sv;
  }
}

// ---------------- bucketed mean aggregation (no global CSR) ----------------
// One block per bucket: stage packed edges to LDS, counting-sort by local node,
// then per-node readlane-free gather (edge list is LDS-broadcast).
__global__ __launch_bounds__(256) void k_agg_b(
    const unsigned short* __restrict__ h, const int* __restrict__ pk,
    const int* __restrict__ base, int E, unsigned short* __restrict__ mean)
{
  __shared__ int stage[CAP];
  __shared__ int lists[CAP];
  __shared__ int hist[BN];
  __shared__ int nofs[BN];   // inclusive scan of hist
  __shared__ int curs[BN];
  const int b = blockIdx.x;
  const int t = threadIdx.x;
  const int bstart = base[b];                       // base[0][b]
  const int bend = (b + 1 < NB) ? base[b+1] : E;
  const int ne = bend - bstart;
  const int wave = t >> 6, lane = t & 63;
  const unsigned* hp = (const unsigned*)h;

  if(ne <= CAP){
    for(int i = t; i < BN; i += 256) hist[i] = 0;
    __syncthreads();
    for(int i = t; i < ne; i += 256){
      const int e = __builtin_nontemporal_load(pk + bstart + i);
      stage[i] = e;
      atomicAdd(&hist[e >> 17], 1);
    }
    __syncthreads();
    if(t < BN) nofs[t] = hist[t];
    __syncthreads();
    for(int d = 1; d < BN; d <<= 1){
      int add = 0;
      if(t < BN && t >= d) add = nofs[t-d];
      __syncthreads();
      if(t < BN) nofs[t] += add;
      __syncthreads();
    }
    if(t < BN) curs[t] = nofs[t] - hist[t];
    __syncthreads();
    for(int i = t; i < ne; i += 256){
      const int e = stage[i];
      const int pos = atomicAdd(&curs[e >> 17], 1);
      lists[pos] = e & 0x1ffff;
    }
    __syncthreads();
    for(int n = wave; n < BN; n += 4){
      const int node = b*BN + n;
      if(node >= N_NODES) break;
      const int deg = hist[n];
      const int nb_ = nofs[n] - deg;
      float a0 = 0.f, a1 = 0.f;
      int e = 0;
      for(; e + 8 <= deg; e += 8){
        unsigned v[8];
        #pragma unroll
        for(int u = 0; u < 8; u++){
          const int s = lists[nb_ + e + u];          // uniform -> LDS broadcast
          v[u] = hp[(size_t)s*64 + lane];
        }
        #pragma unroll
        for(int u = 0; u < 8; u++){
          a0 += bf2f((unsigned short)(v[u] & 0xffffu));
          a1 += bf2f((unsigned short)(v[u] >> 16));
        }
      }
      for(; e < deg; e++){
        const int s = lists[nb_ + e];
        const unsigned vv = hp[(size_t)s*64 + lane];
        a0 += bf2f((unsigned short)(vv & 0xffffu));
        a1 += bf2f((unsigned short)(vv >> 16));
      }
      const float inv = (deg > 0) ? (1.0f/(float)deg) : 0.f;
      a0 *= inv; a1 *= inv;
      const unsigned o = ((unsigned)(unsigned short)f2bf(a1) << 16) | (unsigned)(unsigned short)f2bf(a0);
      ((unsigned*)mean)[(size_t)node*64 + lane] = o;
    }
  } else {
    // overflow fallback (unreachable for random graphs): wave scans whole bucket
    for(int n = wave; n < BN; n += 4){
      const int node = b*BN + n;
      if(node >= N_NODES) break;
      float a0 = 0.f, a1 = 0.f; int deg = 0;
      for(int i = 0; i < ne; i++){
        const int e = pk[bstart + i];
        if((e >> 17) == n){
          const int s = e & 0x1ffff;
          const unsigned vv = hp[(size_t)s*64 + lane];
          a0 += bf2f((unsigned short)(vv & 0xffffu));
          a1 += bf2f((unsigned short)(vv >> 16));
          deg++;
        }
      }
      const float inv = (deg > 0) ? (1.0f/(float)deg) : 0.f;
      a0 *= inv; a1 *= inv;
      const unsigned o = ((unsigned)(unsigned short)f2bf(a1) << 16) | (unsigned)(unsigned short)f2bf(a0);
      ((unsigned*)mean)[(size_t)node*64 + lane] = o;
    }
  }
}

// ---------------- pre GEMM: h0 = x @ W_pre + b_pre  (f32 in, bf16 out) ----------------
__global__ __launch_bounds__(256) void k_gemm_pre(
    const float* __restrict__ x, const unsigned short* __restrict__ wimg,
    const float* __restrict__ b, unsigned short* __restrict__ out)
{
  __shared__ short wlds[8*8*64*8];
  const int t = threadIdx.x;
  {
    short8* dstp = reinterpret_cast<short8*>(wlds);
    const short8* srcp = reinterpret_cast<const short8*>(wimg);
    #pragma unroll
    for(int i = 0; i < 16; i++) dstp[t + i*256] = srcp[t + i*256];
  }
  __syncthreads();
  const int wave = t >> 6, lane = t & 63;
  const int r_in = lane & 15, kg = lane >> 4;
  for(int tile = blockIdx.x*4 + wave; tile < N_NODES/16; tile += gridDim.x*4){
    const int row0 = tile*16;
    const float* xp = x + (size_t)(row0 + r_in)*IN_F + kg*8;
    float4 xa[8], xb[8];
    #pragma unroll
    for(int kb = 0; kb < 8; kb++){
      xa[kb] = *reinterpret_cast<const float4*>(xp + kb*32);
      xb[kb] = *reinterpret_cast<const float4*>(xp + kb*32 + 4);
    }
    f32x4 acc[8];
    #pragma unroll
    for(int ct = 0; ct < 8; ct++) acc[ct] = (f32x4){0.f,0.f,0.f,0.f};
    #pragma unroll
    for(int kb = 0; kb < 8; kb++){
      short8 a;
      a[0]=f2bf(xa[kb].x); a[1]=f2bf(xa[kb].y); a[2]=f2bf(xa[kb].z); a[3]=f2bf(xa[kb].w);
      a[4]=f2bf(xb[kb].x); a[5]=f2bf(xb[kb].y); a[6]=f2bf(xb[kb].z); a[7]=f2bf(xb[kb].w);
      #pragma unroll
      for(int ct = 0; ct < 8; ct++){
        short8 bb = *reinterpret_cast<const short8*>(&wlds[((ct*8+kb)*64+lane)*8]);
        acc[ct] = __builtin_amdgcn_mfma_f32_16x16x32_bf16(a, bb, acc[ct], 0, 0, 0);
      }
    }
    #pragma unroll
    for(int ct = 0; ct < 8; ct++){
      const int col = ct*16 + r_in;
      const float bias = b[col];
      #pragma unroll
      for(int i = 0; i < 4; i++){
        const int row = row0 + kg*4 + i;
        out[(size_t)row*HID + col] = (unsigned short)f2bf(acc[ct][i] + bias);
      }
    }
  }
}

// ------- sage GEMM: out = relu(mean @ Wl + bl + h @ Wr)  (bf16 in/out) -------
__global__ __launch_bounds__(256) void k_gemm_sage(
    const unsigned short* __restrict__ mean, const unsigned short* __restrict__ h,
    const unsigned short* __restrict__ wimg, const float* __restrict__ bl,
    unsigned short* __restrict__ out)
{
  __shared__ short wlds[8*8*64*8];
  const int t = threadIdx.x;
  {
    short8* dstp = reinterpret_cast<short8*>(wlds);
    const short8* srcp = reinterpret_cast<const short8*>(wimg);
    #pragma unroll
    for(int i = 0; i < 16; i++) dstp[t + i*256] = srcp[t + i*256];
  }
  __syncthreads();
  const int wave = t >> 6, lane = t & 63;
  const int r_in = lane & 15, kg = lane >> 4;
  for(int tile = blockIdx.x*4 + wave; tile < N_NODES/16; tile += gridDim.x*4){
    const int row0 = tile*16;
    f32x4 acc[8];
    #pragma unroll
    for(int ct = 0; ct < 8; ct++) acc[ct] = (f32x4){0.f,0.f,0.f,0.f};
    #pragma unroll
    for(int kb = 0; kb < 8; kb++){
      const unsigned short* in = (kb < 4) ? mean : h;
      const int koff = (kb & 3)*32 + kg*8;
      short8 a = *reinterpret_cast<const short8*>(in + (size_t)(row0 + r_in)*HID + koff);
      #pragma unroll
      for(int ct = 0; ct < 8; ct++){
        short8 bb = *reinterpret_cast<const short8*>(&wlds[((ct*8+kb)*64+lane)*8]);
        acc[ct] = __builtin_amdgcn_mfma_f32_16x16x32_bf16(a, bb, acc[ct], 0, 0, 0);
      }
    }
    #pragma unroll
    for(int ct = 0; ct < 8; ct++){
      const int col = ct*16 + r_in;
      const float bias = bl[col];
      #pragma unroll
      for(int i = 0; i < 4; i++){
        const int row = row0 + kg*4 + i;
        float v = fmaxf(acc[ct][i] + bias, 0.f);
        out[(size_t)row*HID + col] = (unsigned short)f2bf(v);
      }
    }
  }
}

// ---------------- post: log_softmax(h @ W_post + b_post), MFMA ----------------
__global__ __launch_bounds__(256) void k_post(
    const unsigned short* __restrict__ h, const unsigned short* __restrict__ wimg,
    const float* __restrict__ b, float* __restrict__ out)
{
  __shared__ short wlds[3*4*64*8];
  __shared__ float bias_s[48];
  const int t = threadIdx.x;
  {
    short8* dstp = reinterpret_cast<short8*>(wlds);
    const short8* srcp = reinterpret_cast<const short8*>(wimg);
    for(int i = t; i < 768; i += 256) dstp[i] = srcp[i];
  }
  if(t < 48) bias_s[t] = (t < NCLS) ? b[t] : -1e30f;
  __syncthreads();
  const int wave = t >> 6, lane = t & 63;
  const int r_in = lane & 15, kg = lane >> 4;
  for(int tile = blockIdx.x*4 + wave; tile < N_NODES/16; tile += gridDim.x*4){
    const int row0 = tile*16;
    f32x4 acc[3];
    #pragma unroll
    for(int ct = 0; ct < 3; ct++) acc[ct] = (f32x4){0.f,0.f,0.f,0.f};
    #pragma unroll
    for(int kb = 0; kb < 4; kb++){
      short8 a = *reinterpret_cast<const short8*>(h + (size_t)(row0 + r_in)*HID + kb*32 + kg*8);
      #pragma unroll
      for(int ct = 0; ct < 3; ct++){
        short8 bb = *reinterpret_cast<const short8*>(&wlds[((ct*4+kb)*64+lane)*8]);
        acc[ct] = __builtin_amdgcn_mfma_f32_16x16x32_bf16(a, bb, acc[ct], 0, 0, 0);
      }
    }
    #pragma unroll
    for(int i = 0; i < 4; i++){
      float v0 = acc[0][i] + bias_s[r_in];
      float v1 = acc[1][i] + bias_s[16 + r_in];
      float v2 = acc[2][i] + bias_s[32 + r_in];
      float m = fmaxf(fmaxf(v0, v1), v2);
      #pragma unroll
      for(int o = 8; o > 0; o >>= 1) m = fmaxf(m, __shfl_xor(m, o));
      float s = expf(v0 - m) + expf(v1 - m) + expf(v2 - m);
      #pragma unroll
      for(int o = 8; o > 0; o >>= 1) s += __shfl_xor(s, o);
      const float ls = m + logf(s);
      const int row = row0 + kg*4 + i;
      float* op = out + (size_t)row*NCLS;
      op[r_in] = v0 - ls;
      op[16 + r_in] = v1 - ls;
      if(r_in < 8) op[32 + r_in] = v2 - ls;
    }
  }
}

extern "C" void kernel_launch(void* const* d_in, const int* in_sizes, int n_in,
                              void* d_out, int out_size, void* d_ws, size_t ws_size,
                              hipStream_t stream)
{
  const float* x      = (const float*)d_in[0];
  const int*   ei     = (const int*)  d_in[1];
  const float* W_pre  = (const float*)d_in[2];
  const float* b_pre  = (const float*)d_in[3];
  const float* Wl0    = (const float*)d_in[4];
  const float* bl0    = (const float*)d_in[5];
  const float* Wr0    = (const float*)d_in[6];
  const float* Wl1    = (const float*)d_in[7];
  const float* bl1    = (const float*)d_in[8];
  const float* Wr1    = (const float*)d_in[9];
  const float* W_post = (const float*)d_in[10];
  const float* b_post = (const float*)d_in[11];
  float* out = (float*)d_out;

  const int E = in_sizes[1] / 2;
  const int* src = ei;
  const int* dst = ei + E;

  char* ws = (char*)d_ws;
  size_t off = 0;
  auto alloc = [&](size_t bytes)->void*{
    void* p = ws + off;
    off += (bytes + 255) & ~(size_t)255;
    return p;
  };
  unsigned short* hA = (unsigned short*)alloc((size_t)N_NODES*HID*2);
  unsigned short* hB = (unsigned short*)alloc((size_t)N_NODES*HID*2);
  unsigned short* hM = (unsigned short*)alloc((size_t)N_NODES*HID*2);
  int* pk    = (int*)alloc((size_t)E*4);
  int* cnt   = (int*)alloc((size_t)NC*NB*4);
  int* base  = (int*)alloc((size_t)NC*NB*4);
  unsigned short* wimg = (unsigned short*)alloc(104448*2);

  // ---- weight pre-pack ----
  k_wprep<<<51, 256, 0, stream>>>(W_pre, Wl0, Wr0, Wl1, Wr1, W_post, wimg);

  // ---- bucketed edge partition (replaces CSR build entirely) ----
  k_hist<<<NC, 256, 0, stream>>>(dst, E, cnt);
  k_bscan<<<1, 1024, 0, stream>>>(cnt, base);
  k_place<<<56, 256, 0, stream>>>(src, dst, E, base, pk);

  // ---- pre linear ----
  k_gemm_pre<<<512, 256, 0, stream>>>(x, wimg, b_pre, hA);

  // ---- SAGE layer 0 ----
  k_agg_b<<<NB, 256, 0, stream>>>(hA, pk, base, E, hM);
  k_gemm_sage<<<1563, 256, 0, stream>>>(hM, hA, wimg + 32768, bl0, hB);

  // ---- SAGE layer 1 ----
  k_agg_b<<<NB, 256, 0, stream>>>(hB, pk, base, E, hM);
  k_gemm_sage<<<1563, 256, 0, stream>>>(hM, hB, wimg + 65536, bl1, hA);

  // ---- post linear + log_softmax ----
  k_post<<<1563, 256, 0, stream>>>(hA, wimg + 98304, b_post, out);
}

// Round 11
// 378.579 us; speedup vs baseline: 1.2215x; 1.1059x over previous
//
#include <hip/hip_runtime.h>
#include <hip/hip_bf16.h>
#include <math.h>

#define N_NODES 100000
#define IN_F 256
#define HID 128
#define NCLS 40

#define NB 782           // buckets of BN consecutive nodes (dst>>7)
#define BN 128
#define NC 49            // chunks of CSZ2 edges
#define CSZ2 32768
#define CAP 4096         // max staged edges per bucket (avg ~2053)

typedef __attribute__((ext_vector_type(8))) short short8;
typedef __attribute__((ext_vector_type(4))) float f32x4;

__device__ __forceinline__ short f2bf(float f){
  union { float f; unsigned u; } x; x.f = f;
  unsigned r = (x.u + 0x7fffu + ((x.u >> 16) & 1u)) >> 16;
  return (short)r;
}
__device__ __forceinline__ float bf2f(unsigned short u){
  union { unsigned u; float f; } x; x.u = ((unsigned)u) << 16;
  return x.f;
}

// ---------------- weight pre-pack: f32 -> bf16 MFMA B-frag images ----------------
__global__ __launch_bounds__(256) void k_wprep(
    const float* __restrict__ Wpre, const float* __restrict__ Wl0,
    const float* __restrict__ Wr0,  const float* __restrict__ Wl1,
    const float* __restrict__ Wr1,  const float* __restrict__ Wpost,
    unsigned short* __restrict__ img)
{
  const int g = blockIdx.x*256 + threadIdx.x;   // one short8 per thread
  if(g >= 13056) return;
  const int base = g*8;
  unsigned short v[8];
  if(base < 98304){
    const int which = base >> 15;               // 0=pre, 1=L0, 2=L1
    const int idx = base & 32767;
    const int l = (idx >> 3) & 63, kb = (idx >> 9) & 7, ct = idx >> 12;
    const int col = ct*16 + (l & 15);
    const float* Wsrc; int kbase;
    if(which == 0){ Wsrc = Wpre; kbase = kb*32 + (l>>4)*8; }
    else{
      Wsrc = (which==1) ? ((kb<4) ? Wl0 : Wr0) : ((kb<4) ? Wl1 : Wr1);
      kbase = (kb&3)*32 + (l>>4)*8;
    }
    #pragma unroll
    for(int j = 0; j < 8; j++) v[j] = (unsigned short)f2bf(Wsrc[(size_t)(kbase+j)*HID + col]);
  } else {
    const int idx = base - 98304;               // post image [3][4][64][8]
    const int l = (idx >> 3) & 63, kb = (idx >> 9) & 3, ct = idx >> 11;
    const int col = ct*16 + (l & 15);
    const int kbase = kb*32 + (l>>4)*8;
    #pragma unroll
    for(int j = 0; j < 8; j++)
      v[j] = (col < NCLS) ? (unsigned short)f2bf(Wpost[(size_t)(kbase+j)*NCLS + col]) : 0;
  }
  *reinterpret_cast<short8*>(img + base) = *reinterpret_cast<const short8*>(v);
}

// ---------------- bucketed edge partition ----------------
__global__ __launch_bounds__(256) void k_hist(const int* __restrict__ dst, int E,
                                              int* __restrict__ cnt){
  __shared__ int hist[NB];
  const int c = blockIdx.x;
  for(int i = threadIdx.x; i < NB; i += 256) hist[i] = 0;
  __syncthreads();
  const int s0 = c*CSZ2, s1 = min(s0 + CSZ2, E);
  for(int i = s0 + threadIdx.x; i < s1; i += 256)
    atomicAdd(&hist[(unsigned)__builtin_nontemporal_load(dst + i) >> 7], 1);
  __syncthreads();
  for(int i = threadIdx.x; i < NB; i += 256) cnt[c*NB + i] = hist[i];   // [c][b]
}

__global__ __launch_bounds__(1024) void k_bscan(const int* __restrict__ cnt,
                                                int* __restrict__ base){
  __shared__ int s[1024];
  const int t = threadIdx.x;
  int tot = 0;
  if(t < NB){
    for(int c = 0; c < NC; c++){
      const int v = cnt[c*NB + t];
      base[c*NB + t] = tot;          // within-bucket exclusive
      tot += v;
    }
  }
  s[t] = tot; __syncthreads();
  for(int d = 1; d < 1024; d <<= 1){
    int add = (t >= d) ? s[t-d] : 0;
    __syncthreads();
    s[t] += add;
    __syncthreads();
  }
  const int bb = (t > 0) ? s[t-1] : 0;
  if(t < NB)
    for(int c = 0; c < NC; c++) base[c*NB + t] += bb;
}

__global__ __launch_bounds__(256) void k_place(const int* __restrict__ src,
                                               const int* __restrict__ dst, int E,
                                               const int* __restrict__ base,
                                               int* __restrict__ pk){
  const int g = blockIdx.x;            // 56 blocks: 8 XCD groups x 7
  const int c = (g & 7)*7 + (g >> 3);
  if(c >= NC) return;
  __shared__ int cur[NB];
  for(int i = threadIdx.x; i < NB; i += 256) cur[i] = base[c*NB + i];
  __syncthreads();
  const int s0 = c*CSZ2, s1 = min(s0 + CSZ2, E);
  for(int i = s0 + threadIdx.x; i < s1; i += 256){
    const int d  = __builtin_nontemporal_load(dst + i);
    const int sv = __builtin_nontemporal_load(src + i);
    const int pos = atomicAdd(&cur[(unsigned)d >> 7], 1);
    pk[pos] = ((d & 127) << 17) | sv;
  }
}

// ---------------- bucketed mean aggregation ----------------
// 512 threads / 8 waves per block: grid is only NB=782 blocks, so per-block
// wave count (not LDS) sets occupancy — 8 waves x 3 blocks/CU = 24 waves/CU
// vs 12 before. More independent 256B row-gathers in flight = more BW.
__global__ __launch_bounds__(512) void k_agg_b(
    const unsigned short* __restrict__ h, const int* __restrict__ pk,
    const int* __restrict__ base, int E, unsigned short* __restrict__ mean)
{
  __shared__ int stage[CAP];
  __shared__ int lists[CAP];
  __shared__ int hist[BN];
  __shared__ int nofs[BN];   // inclusive scan of hist
  __shared__ int curs[BN];
  const int b = blockIdx.x;
  const int t = threadIdx.x;
  const int bstart = base[b];                       // base[0][b]
  const int bend = (b + 1 < NB) ? base[b+1] : E;
  const int ne = bend - bstart;
  const int wave = t >> 6, lane = t & 63;
  const unsigned* hp = (const unsigned*)h;

  if(ne <= CAP){
    for(int i = t; i < BN; i += 512) hist[i] = 0;
    __syncthreads();
    for(int i = t; i < ne; i += 512){
      const int e = __builtin_nontemporal_load(pk + bstart + i);
      stage[i] = e;
      atomicAdd(&hist[e >> 17], 1);
    }
    __syncthreads();
    if(t < BN) nofs[t] = hist[t];
    __syncthreads();
    for(int d = 1; d < BN; d <<= 1){
      int add = 0;
      if(t < BN && t >= d) add = nofs[t-d];
      __syncthreads();
      if(t < BN) nofs[t] += add;
      __syncthreads();
    }
    if(t < BN) curs[t] = nofs[t] - hist[t];
    __syncthreads();
    for(int i = t; i < ne; i += 512){
      const int e = stage[i];
      const int pos = atomicAdd(&curs[e >> 17], 1);
      lists[pos] = e & 0x1ffff;
    }
    __syncthreads();
    for(int n = wave; n < BN; n += 8){
      const int node = b*BN + n;
      if(node >= N_NODES) break;
      const int deg = hist[n];
      const int nb_ = nofs[n] - deg;
      float a0 = 0.f, a1 = 0.f;
      int e = 0;
      for(; e + 8 <= deg; e += 8){
        unsigned v[8];
        #pragma unroll
        for(int u = 0; u < 8; u++){
          const int s = lists[nb_ + e + u];          // uniform -> LDS broadcast
          v[u] = hp[(size_t)s*64 + lane];
        }
        #pragma unroll
        for(int u = 0; u < 8; u++){
          a0 += bf2f((unsigned short)(v[u] & 0xffffu));
          a1 += bf2f((unsigned short)(v[u] >> 16));
        }
      }
      for(; e < deg; e++){
        const int s = lists[nb_ + e];
        const unsigned vv = hp[(size_t)s*64 + lane];
        a0 += bf2f((unsigned short)(vv & 0xffffu));
        a1 += bf2f((unsigned short)(vv >> 16));
      }
      const float inv = (deg > 0) ? (1.0f/(float)deg) : 0.f;
      a0 *= inv; a1 *= inv;
      const unsigned o = ((unsigned)(unsigned short)f2bf(a1) << 16) | (unsigned)(unsigned short)f2bf(a0);
      ((unsigned*)mean)[(size_t)node*64 + lane] = o;
    }
  } else {
    // overflow fallback (unreachable for random graphs)
    for(int n = wave; n < BN; n += 8){
      const int node = b*BN + n;
      if(node >= N_NODES) break;
      float a0 = 0.f, a1 = 0.f; int deg = 0;
      for(int i = 0; i < ne; i++){
        const int e = pk[bstart + i];
        if((e >> 17) == n){
          const int s = e & 0x1ffff;
          const unsigned vv = hp[(size_t)s*64 + lane];
          a0 += bf2f((unsigned short)(vv & 0xffffu));
          a1 += bf2f((unsigned short)(vv >> 16));
          deg++;
        }
      }
      const float inv = (deg > 0) ? (1.0f/(float)deg) : 0.f;
      a0 *= inv; a1 *= inv;
      const unsigned o = ((unsigned)(unsigned short)f2bf(a1) << 16) | (unsigned)(unsigned short)f2bf(a0);
      ((unsigned*)mean)[(size_t)node*64 + lane] = o;
    }
  }
}

// ---------------- pre GEMM: h0 = x @ W_pre + b_pre  (f32 in, bf16 out) ----------------
__global__ __launch_bounds__(256) void k_gemm_pre(
    const float* __restrict__ x, const unsigned short* __restrict__ wimg,
    const float* __restrict__ b, unsigned short* __restrict__ out)
{
  __shared__ short wlds[8*8*64*8];
  const int t = threadIdx.x;
  {
    short8* dstp = reinterpret_cast<short8*>(wlds);
    const short8* srcp = reinterpret_cast<const short8*>(wimg);
    #pragma unroll
    for(int i = 0; i < 16; i++) dstp[t + i*256] = srcp[t + i*256];
  }
  __syncthreads();
  const int wave = t >> 6, lane = t & 63;
  const int r_in = lane & 15, kg = lane >> 4;
  for(int tile = blockIdx.x*4 + wave; tile < N_NODES/16; tile += gridDim.x*4){
    const int row0 = tile*16;
    const float* xp = x + (size_t)(row0 + r_in)*IN_F + kg*8;
    float4 xa[8], xb[8];
    #pragma unroll
    for(int kb = 0; kb < 8; kb++){
      xa[kb] = *reinterpret_cast<const float4*>(xp + kb*32);
      xb[kb] = *reinterpret_cast<const float4*>(xp + kb*32 + 4);
    }
    f32x4 acc[8];
    #pragma unroll
    for(int ct = 0; ct < 8; ct++) acc[ct] = (f32x4){0.f,0.f,0.f,0.f};
    #pragma unroll
    for(int kb = 0; kb < 8; kb++){
      short8 a;
      a[0]=f2bf(xa[kb].x); a[1]=f2bf(xa[kb].y); a[2]=f2bf(xa[kb].z); a[3]=f2bf(xa[kb].w);
      a[4]=f2bf(xb[kb].x); a[5]=f2bf(xb[kb].y); a[6]=f2bf(xb[kb].z); a[7]=f2bf(xb[kb].w);
      #pragma unroll
      for(int ct = 0; ct < 8; ct++){
        short8 bb = *reinterpret_cast<const short8*>(&wlds[((ct*8+kb)*64+lane)*8]);
        acc[ct] = __builtin_amdgcn_mfma_f32_16x16x32_bf16(a, bb, acc[ct], 0, 0, 0);
      }
    }
    #pragma unroll
    for(int ct = 0; ct < 8; ct++){
      const int col = ct*16 + r_in;
      const float bias = b[col];
      #pragma unroll
      for(int i = 0; i < 4; i++){
        const int row = row0 + kg*4 + i;
        out[(size_t)row*HID + col] = (unsigned short)f2bf(acc[ct][i] + bias);
      }
    }
  }
}

// ------- sage GEMM: out = relu(mean @ Wl + bl + h @ Wr)  (bf16 in/out) -------
__global__ __launch_bounds__(256) void k_gemm_sage(
    const unsigned short* __restrict__ mean, const unsigned short* __restrict__ h,
    const unsigned short* __restrict__ wimg, const float* __restrict__ bl,
    unsigned short* __restrict__ out)
{
  __shared__ short wlds[8*8*64*8];
  const int t = threadIdx.x;
  {
    short8* dstp = reinterpret_cast<short8*>(wlds);
    const short8* srcp = reinterpret_cast<const short8*>(wimg);
    #pragma unroll
    for(int i = 0; i < 16; i++) dstp[t + i*256] = srcp[t + i*256];
  }
  __syncthreads();
  const int wave = t >> 6, lane = t & 63;
  const int r_in = lane & 15, kg = lane >> 4;
  for(int tile = blockIdx.x*4 + wave; tile < N_NODES/16; tile += gridDim.x*4){
    const int row0 = tile*16;
    f32x4 acc[8];
    #pragma unroll
    for(int ct = 0; ct < 8; ct++) acc[ct] = (f32x4){0.f,0.f,0.f,0.f};
    #pragma unroll
    for(int kb = 0; kb < 8; kb++){
      const unsigned short* in = (kb < 4) ? mean : h;
      const int koff = (kb & 3)*32 + kg*8;
      short8 a = *reinterpret_cast<const short8*>(in + (size_t)(row0 + r_in)*HID + koff);
      #pragma unroll
      for(int ct = 0; ct < 8; ct++){
        short8 bb = *reinterpret_cast<const short8*>(&wlds[((ct*8+kb)*64+lane)*8]);
        acc[ct] = __builtin_amdgcn_mfma_f32_16x16x32_bf16(a, bb, acc[ct], 0, 0, 0);
      }
    }
    #pragma unroll
    for(int ct = 0; ct < 8; ct++){
      const int col = ct*16 + r_in;
      const float bias = bl[col];
      #pragma unroll
      for(int i = 0; i < 4; i++){
        const int row = row0 + kg*4 + i;
        float v = fmaxf(acc[ct][i] + bias, 0.f);
        out[(size_t)row*HID + col] = (unsigned short)f2bf(v);
      }
    }
  }
}

// ---------------- post: log_softmax(h @ W_post + b_post), MFMA ----------------
__global__ __launch_bounds__(256) void k_post(
    const unsigned short* __restrict__ h, const unsigned short* __restrict__ wimg,
    const float* __restrict__ b, float* __restrict__ out)
{
  __shared__ short wlds[3*4*64*8];
  __shared__ float bias_s[48];
  const int t = threadIdx.x;
  {
    short8* dstp = reinterpret_cast<short8*>(wlds);
    const short8* srcp = reinterpret_cast<const short8*>(wimg);
    for(int i = t; i < 768; i += 256) dstp[i] = srcp[i];
  }
  if(t < 48) bias_s[t] = (t < NCLS) ? b[t] : -1e30f;
  __syncthreads();
  const int wave = t >> 6, lane = t & 63;
  const int r_in = lane & 15, kg = lane >> 4;
  for(int tile = blockIdx.x*4 + wave; tile < N_NODES/16; tile += gridDim.x*4){
    const int row0 = tile*16;
    f32x4 acc[3];
    #pragma unroll
    for(int ct = 0; ct < 3; ct++) acc[ct] = (f32x4){0.f,0.f,0.f,0.f};
    #pragma unroll
    for(int kb = 0; kb < 4; kb++){
      short8 a = *reinterpret_cast<const short8*>(h + (size_t)(row0 + r_in)*HID + kb*32 + kg*8);
      #pragma unroll
      for(int ct = 0; ct < 3; ct++){
        short8 bb = *reinterpret_cast<const short8*>(&wlds[((ct*4+kb)*64+lane)*8]);
        acc[ct] = __builtin_amdgcn_mfma_f32_16x16x32_bf16(a, bb, acc[ct], 0, 0, 0);
      }
    }
    #pragma unroll
    for(int i = 0; i < 4; i++){
      float v0 = acc[0][i] + bias_s[r_in];
      float v1 = acc[1][i] + bias_s[16 + r_in];
      float v2 = acc[2][i] + bias_s[32 + r_in];
      float m = fmaxf(fmaxf(v0, v1), v2);
      #pragma unroll
      for(int o = 8; o > 0; o >>= 1) m = fmaxf(m, __shfl_xor(m, o));
      float s = expf(v0 - m) + expf(v1 - m) + expf(v2 - m);
      #pragma unroll
      for(int o = 8; o > 0; o >>= 1) s += __shfl_xor(s, o);
      const float ls = m + logf(s);
      const int row = row0 + kg*4 + i;
      float* op = out + (size_t)row*NCLS;
      op[r_in] = v0 - ls;
      op[16 + r_in] = v1 - ls;
      if(r_in < 8) op[32 + r_in] = v2 - ls;
    }
  }
}

extern "C" void kernel_launch(void* const* d_in, const int* in_sizes, int n_in,
                              void* d_out, int out_size, void* d_ws, size_t ws_size,
                              hipStream_t stream)
{
  const float* x      = (const float*)d_in[0];
  const int*   ei     = (const int*)  d_in[1];
  const float* W_pre  = (const float*)d_in[2];
  const float* b_pre  = (const float*)d_in[3];
  const float* Wl0    = (const float*)d_in[4];
  const float* bl0    = (const float*)d_in[5];
  const float* Wr0    = (const float*)d_in[6];
  const float* Wl1    = (const float*)d_in[7];
  const float* bl1    = (const float*)d_in[8];
  const float* Wr1    = (const float*)d_in[9];
  const float* W_post = (const float*)d_in[10];
  const float* b_post = (const float*)d_in[11];
  float* out = (float*)d_out;

  const int E = in_sizes[1] / 2;
  const int* src = ei;
  const int* dst = ei + E;

  char* ws = (char*)d_ws;
  size_t off = 0;
  auto alloc = [&](size_t bytes)->void*{
    void* p = ws + off;
    off += (bytes + 255) & ~(size_t)255;
    return p;
  };
  unsigned short* hA = (unsigned short*)alloc((size_t)N_NODES*HID*2);
  unsigned short* hB = (unsigned short*)alloc((size_t)N_NODES*HID*2);
  unsigned short* hM = (unsigned short*)alloc((size_t)N_NODES*HID*2);
  int* pk    = (int*)alloc((size_t)E*4);
  int* cnt   = (int*)alloc((size_t)NC*NB*4);
  int* base  = (int*)alloc((size_t)NC*NB*4);
  unsigned short* wimg = (unsigned short*)alloc(104448*2);

  // ---- weight pre-pack ----
  k_wprep<<<51, 256, 0, stream>>>(W_pre, Wl0, Wr0, Wl1, Wr1, W_post, wimg);

  // ---- bucketed edge partition ----
  k_hist<<<NC, 256, 0, stream>>>(dst, E, cnt);
  k_bscan<<<1, 1024, 0, stream>>>(cnt, base);
  k_place<<<56, 256, 0, stream>>>(src, dst, E, base, pk);

  // ---- pre linear ----
  k_gemm_pre<<<512, 256, 0, stream>>>(x, wimg, b_pre, hA);

  // ---- SAGE layer 0 ----
  k_agg_b<<<NB, 512, 0, stream>>>(hA, pk, base, E, hM);
  k_gemm_sage<<<1563, 256, 0, stream>>>(hM, hA, wimg + 32768, bl0, hB);

  // ---- SAGE layer 1 ----
  k_agg_b<<<NB, 512, 0, stream>>>(hB, pk, base, E, hM);
  k_gemm_sage<<<1563, 256, 0, stream>>>(hM, hB, wimg + 65536, bl1, hA);

  // ---- post linear + log_softmax ----
  k_post<<<1563, 256, 0, stream>>>(hA, wimg + 98304, b_post, out);
}

// Round 12
// 279.974 us; speedup vs baseline: 1.6517x; 1.3522x over previous
//
#include <hip/hip_runtime.h>
#include <hip/hip_bf16.h>
#include <math.h>

#define N_NODES 100000
#define IN_F 256
#define HID 128
#define NCLS 40

#define NB 782           // buckets of BN consecutive nodes (dst>>7)
#define BN 128
#define NC 448           // chunks of CSZ2 edges (448*3584 = 1,605,632 >= E)
#define CSZ2 3584
#define CAP 4096         // max staged edges per bucket (avg ~2053)

typedef __attribute__((ext_vector_type(8))) short short8;
typedef __attribute__((ext_vector_type(4))) float f32x4;

__device__ __forceinline__ short f2bf(float f){
  union { float f; unsigned u; } x; x.f = f;
  unsigned r = (x.u + 0x7fffu + ((x.u >> 16) & 1u)) >> 16;
  return (short)r;
}
__device__ __forceinline__ float bf2f(unsigned short u){
  union { unsigned u; float f; } x; x.u = ((unsigned)u) << 16;
  return x.f;
}

// ---------------- weight pre-pack: f32 -> bf16 MFMA B-frag images ----------------
__global__ __launch_bounds__(256) void k_wprep(
    const float* __restrict__ Wpre, const float* __restrict__ Wl0,
    const float* __restrict__ Wr0,  const float* __restrict__ Wl1,
    const float* __restrict__ Wr1,  const float* __restrict__ Wpost,
    unsigned short* __restrict__ img)
{
  const int g = blockIdx.x*256 + threadIdx.x;   // one short8 per thread
  if(g >= 13056) return;
  const int base = g*8;
  unsigned short v[8];
  if(base < 98304){
    const int which = base >> 15;               // 0=pre, 1=L0, 2=L1
    const int idx = base & 32767;
    const int l = (idx >> 3) & 63, kb = (idx >> 9) & 7, ct = idx >> 12;
    const int col = ct*16 + (l & 15);
    const float* Wsrc; int kbase;
    if(which == 0){ Wsrc = Wpre; kbase = kb*32 + (l>>4)*8; }
    else{
      Wsrc = (which==1) ? ((kb<4) ? Wl0 : Wr0) : ((kb<4) ? Wl1 : Wr1);
      kbase = (kb&3)*32 + (l>>4)*8;
    }
    #pragma unroll
    for(int j = 0; j < 8; j++) v[j] = (unsigned short)f2bf(Wsrc[(size_t)(kbase+j)*HID + col]);
  } else {
    const int idx = base - 98304;               // post image [3][4][64][8]
    const int l = (idx >> 3) & 63, kb = (idx >> 9) & 3, ct = idx >> 11;
    const int col = ct*16 + (l & 15);
    const int kbase = kb*32 + (l>>4)*8;
    #pragma unroll
    for(int j = 0; j < 8; j++)
      v[j] = (col < NCLS) ? (unsigned short)f2bf(Wpost[(size_t)(kbase+j)*NCLS + col]) : 0;
  }
  *reinterpret_cast<short8*>(img + base) = *reinterpret_cast<const short8*>(v);
}

// ---------------- bucketed edge partition ----------------
// Per-chunk bucket histogram (448 small chunks -> real occupancy).
__global__ __launch_bounds__(256) void k_hist(const int* __restrict__ dst, int E,
                                              int* __restrict__ cnt){
  __shared__ int hist[NB];
  const int c = blockIdx.x;
  for(int i = threadIdx.x; i < NB; i += 256) hist[i] = 0;
  __syncthreads();
  const int s0 = c*CSZ2, s1 = min(s0 + CSZ2, E);
  for(int i = s0 + threadIdx.x; i < s1; i += 256)
    atomicAdd(&hist[(unsigned)__builtin_nontemporal_load(dst + i) >> 7], 1);
  __syncthreads();
  for(int i = threadIdx.x; i < NB; i += 256) cnt[c*NB + i] = hist[i];   // [c][b]
}

// Per-bucket exclusive scan over the 448 chunks (one block per bucket).
__global__ __launch_bounds__(256) void k_bscanA(const int* __restrict__ cnt,
                                                int* __restrict__ wbase,
                                                int* __restrict__ btot){
  __shared__ int s[256];
  const int b = blockIdx.x;
  const int t = threadIdx.x;
  int v0 = 0, v1 = 0;
  if(2*t < NC)     v0 = cnt[(2*t)*NB + b];
  if(2*t + 1 < NC) v1 = cnt[(2*t+1)*NB + b];
  s[t] = v0 + v1; __syncthreads();
  for(int d = 1; d < 256; d <<= 1){
    int add = (t >= d) ? s[t-d] : 0;
    __syncthreads();
    s[t] += add;
    __syncthreads();
  }
  const int ex = (t > 0) ? s[t-1] : 0;
  if(2*t < NC)     wbase[(2*t)*NB + b] = ex;
  if(2*t + 1 < NC) wbase[(2*t+1)*NB + b] = ex + v0;
  if(t == 255) btot[b] = s[255];
}

// Exclusive scan of bucket totals -> bucket starts (bstart[NB] = E).
__global__ __launch_bounds__(1024) void k_bscanB(const int* __restrict__ btot,
                                                 int* __restrict__ bstart, int E){
  __shared__ int s[1024];
  const int t = threadIdx.x;
  int v = (t < NB) ? btot[t] : 0;
  s[t] = v; __syncthreads();
  for(int d = 1; d < 1024; d <<= 1){
    int add = (t >= d) ? s[t-d] : 0;
    __syncthreads();
    s[t] += add;
    __syncthreads();
  }
  if(t < NB) bstart[t] = s[t] - v;
  if(t == 0) bstart[NB] = E;
}

// Place packed edges ((dst&127)<<17 | src) via LDS cursors. Chunk->block map
// c = (g&7)*56 + (g>>3): consecutive chunks of a bucket run on the SAME XCD,
// so run-boundary line sharing stays inside one coherent L2 (r6-r9 lesson).
__global__ __launch_bounds__(256) void k_place(const int* __restrict__ src,
                                               const int* __restrict__ dst, int E,
                                               const int* __restrict__ wbase,
                                               const int* __restrict__ bstart,
                                               int* __restrict__ pk){
  const int g = blockIdx.x;
  const int c = (g & 7)*(NC/8) + (g >> 3);
  __shared__ int cur[NB];
  for(int i = threadIdx.x; i < NB; i += 256)
    cur[i] = wbase[c*NB + i] + bstart[i];
  __syncthreads();
  const int s0 = c*CSZ2, s1 = min(s0 + CSZ2, E);
  for(int i = s0 + threadIdx.x; i < s1; i += 256){
    const int d  = __builtin_nontemporal_load(dst + i);
    const int sv = __builtin_nontemporal_load(src + i);
    const int pos = atomicAdd(&cur[(unsigned)d >> 7], 1);
    pk[pos] = ((d & 127) << 17) | sv;
  }
}

// ---------------- bucketed mean aggregation ----------------
__global__ __launch_bounds__(512) void k_agg_b(
    const unsigned short* __restrict__ h, const int* __restrict__ pk,
    const int* __restrict__ bstart, unsigned short* __restrict__ mean)
{
  __shared__ int stage[CAP];
  __shared__ int lists[CAP];
  __shared__ int hist[BN];
  __shared__ int nofs[BN];   // inclusive scan of hist
  __shared__ int curs[BN];
  const int b = blockIdx.x;
  const int t = threadIdx.x;
  const int bs = bstart[b];
  const int be = bstart[b+1];
  const int ne = be - bs;
  const int wave = t >> 6, lane = t & 63;
  const unsigned* hp = (const unsigned*)h;

  if(ne <= CAP){
    for(int i = t; i < BN; i += 512) hist[i] = 0;
    __syncthreads();
    for(int i = t; i < ne; i += 512){
      const int e = __builtin_nontemporal_load(pk + bs + i);
      stage[i] = e;
      atomicAdd(&hist[e >> 17], 1);
    }
    __syncthreads();
    if(t < BN) nofs[t] = hist[t];
    __syncthreads();
    for(int d = 1; d < BN; d <<= 1){
      int add = 0;
      if(t < BN && t >= d) add = nofs[t-d];
      __syncthreads();
      if(t < BN) nofs[t] += add;
      __syncthreads();
    }
    if(t < BN) curs[t] = nofs[t] - hist[t];
    __syncthreads();
    for(int i = t; i < ne; i += 512){
      const int e = stage[i];
      const int pos = atomicAdd(&curs[e >> 17], 1);
      lists[pos] = e & 0x1ffff;
    }
    __syncthreads();
    for(int n = wave; n < BN; n += 8){
      const int node = b*BN + n;
      if(node >= N_NODES) break;
      const int deg = hist[n];
      const int nb_ = nofs[n] - deg;
      float a0 = 0.f, a1 = 0.f;
      int e = 0;
      for(; e + 8 <= deg; e += 8){
        unsigned v[8];
        #pragma unroll
        for(int u = 0; u < 8; u++){
          const int s = lists[nb_ + e + u];          // uniform -> LDS broadcast
          v[u] = hp[(size_t)s*64 + lane];
        }
        #pragma unroll
        for(int u = 0; u < 8; u++){
          a0 += bf2f((unsigned short)(v[u] & 0xffffu));
          a1 += bf2f((unsigned short)(v[u] >> 16));
        }
      }
      for(; e < deg; e++){
        const int s = lists[nb_ + e];
        const unsigned vv = hp[(size_t)s*64 + lane];
        a0 += bf2f((unsigned short)(vv & 0xffffu));
        a1 += bf2f((unsigned short)(vv >> 16));
      }
      const float inv = (deg > 0) ? (1.0f/(float)deg) : 0.f;
      a0 *= inv; a1 *= inv;
      const unsigned o = ((unsigned)(unsigned short)f2bf(a1) << 16) | (unsigned)(unsigned short)f2bf(a0);
      ((unsigned*)mean)[(size_t)node*64 + lane] = o;
    }
  } else {
    // overflow fallback (unreachable for random graphs)
    for(int n = wave; n < BN; n += 8){
      const int node = b*BN + n;
      if(node >= N_NODES) break;
      float a0 = 0.f, a1 = 0.f; int deg = 0;
      for(int i = 0; i < ne; i++){
        const int e = pk[bs + i];
        if((e >> 17) == n){
          const int s = e & 0x1ffff;
          const unsigned vv = hp[(size_t)s*64 + lane];
          a0 += bf2f((unsigned short)(vv & 0xffffu));
          a1 += bf2f((unsigned short)(vv >> 16));
          deg++;
        }
      }
      const float inv = (deg > 0) ? (1.0f/(float)deg) : 0.f;
      a0 *= inv; a1 *= inv;
      const unsigned o = ((unsigned)(unsigned short)f2bf(a1) << 16) | (unsigned)(unsigned short)f2bf(a0);
      ((unsigned*)mean)[(size_t)node*64 + lane] = o;
    }
  }
}

// ---------------- pre GEMM: h0 = x @ W_pre + b_pre  (f32 in, bf16 out) ----------------
__global__ __launch_bounds__(256) void k_gemm_pre(
    const float* __restrict__ x, const unsigned short* __restrict__ wimg,
    const float* __restrict__ b, unsigned short* __restrict__ out)
{
  __shared__ short wlds[8*8*64*8];
  const int t = threadIdx.x;
  {
    short8* dstp = reinterpret_cast<short8*>(wlds);
    const short8* srcp = reinterpret_cast<const short8*>(wimg);
    #pragma unroll
    for(int i = 0; i < 16; i++) dstp[t + i*256] = srcp[t + i*256];
  }
  __syncthreads();
  const int wave = t >> 6, lane = t & 63;
  const int r_in = lane & 15, kg = lane >> 4;
  for(int tile = blockIdx.x*4 + wave; tile < N_NODES/16; tile += gridDim.x*4){
    const int row0 = tile*16;
    const float* xp = x + (size_t)(row0 + r_in)*IN_F + kg*8;
    float4 xa[8], xb[8];
    #pragma unroll
    for(int kb = 0; kb < 8; kb++){
      xa[kb] = *reinterpret_cast<const float4*>(xp + kb*32);
      xb[kb] = *reinterpret_cast<const float4*>(xp + kb*32 + 4);
    }
    f32x4 acc[8];
    #pragma unroll
    for(int ct = 0; ct < 8; ct++) acc[ct] = (f32x4){0.f,0.f,0.f,0.f};
    #pragma unroll
    for(int kb = 0; kb < 8; kb++){
      short8 a;
      a[0]=f2bf(xa[kb].x); a[1]=f2bf(xa[kb].y); a[2]=f2bf(xa[kb].z); a[3]=f2bf(xa[kb].w);
      a[4]=f2bf(xb[kb].x); a[5]=f2bf(xb[kb].y); a[6]=f2bf(xb[kb].z); a[7]=f2bf(xb[kb].w);
      #pragma unroll
      for(int ct = 0; ct < 8; ct++){
        short8 bb = *reinterpret_cast<const short8*>(&wlds[((ct*8+kb)*64+lane)*8]);
        acc[ct] = __builtin_amdgcn_mfma_f32_16x16x32_bf16(a, bb, acc[ct], 0, 0, 0);
      }
    }
    #pragma unroll
    for(int ct = 0; ct < 8; ct++){
      const int col = ct*16 + r_in;
      const float bias = b[col];
      #pragma unroll
      for(int i = 0; i < 4; i++){
        const int row = row0 + kg*4 + i;
        out[(size_t)row*HID + col] = (unsigned short)f2bf(acc[ct][i] + bias);
      }
    }
  }
}

// ------- sage GEMM: out = relu(mean @ Wl + bl + h @ Wr)  (bf16 in/out) -------
__global__ __launch_bounds__(256) void k_gemm_sage(
    const unsigned short* __restrict__ mean, const unsigned short* __restrict__ h,
    const unsigned short* __restrict__ wimg, const float* __restrict__ bl,
    unsigned short* __restrict__ out)
{
  __shared__ short wlds[8*8*64*8];
  const int t = threadIdx.x;
  {
    short8* dstp = reinterpret_cast<short8*>(wlds);
    const short8* srcp = reinterpret_cast<const short8*>(wimg);
    #pragma unroll
    for(int i = 0; i < 16; i++) dstp[t + i*256] = srcp[t + i*256];
  }
  __syncthreads();
  const int wave = t >> 6, lane = t & 63;
  const int r_in = lane & 15, kg = lane >> 4;
  for(int tile = blockIdx.x*4 + wave; tile < N_NODES/16; tile += gridDim.x*4){
    const int row0 = tile*16;
    f32x4 acc[8];
    #pragma unroll
    for(int ct = 0; ct < 8; ct++) acc[ct] = (f32x4){0.f,0.f,0.f,0.f};
    #pragma unroll
    for(int kb = 0; kb < 8; kb++){
      const unsigned short* in = (kb < 4) ? mean : h;
      const int koff = (kb & 3)*32 + kg*8;
      short8 a = *reinterpret_cast<const short8*>(in + (size_t)(row0 + r_in)*HID + koff);
      #pragma unroll
      for(int ct = 0; ct < 8; ct++){
        short8 bb = *reinterpret_cast<const short8*>(&wlds[((ct*8+kb)*64+lane)*8]);
        acc[ct] = __builtin_amdgcn_mfma_f32_16x16x32_bf16(a, bb, acc[ct], 0, 0, 0);
      }
    }
    #pragma unroll
    for(int ct = 0; ct < 8; ct++){
      const int col = ct*16 + r_in;
      const float bias = bl[col];
      #pragma unroll
      for(int i = 0; i < 4; i++){
        const int row = row0 + kg*4 + i;
        float v = fmaxf(acc[ct][i] + bias, 0.f);
        out[(size_t)row*HID + col] = (unsigned short)f2bf(v);
      }
    }
  }
}

// ---------------- post: log_softmax(h @ W_post + b_post), MFMA ----------------
__global__ __launch_bounds__(256) void k_post(
    const unsigned short* __restrict__ h, const unsigned short* __restrict__ wimg,
    const float* __restrict__ b, float* __restrict__ out)
{
  __shared__ short wlds[3*4*64*8];
  __shared__ float bias_s[48];
  const int t = threadIdx.x;
  {
    short8* dstp = reinterpret_cast<short8*>(wlds);
    const short8* srcp = reinterpret_cast<const short8*>(wimg);
    for(int i = t; i < 768; i += 256) dstp[i] = srcp[i];
  }
  if(t < 48) bias_s[t] = (t < NCLS) ? b[t] : -1e30f;
  __syncthreads();
  const int wave = t >> 6, lane = t & 63;
  const int r_in = lane & 15, kg = lane >> 4;
  for(int tile = blockIdx.x*4 + wave; tile < N_NODES/16; tile += gridDim.x*4){
    const int row0 = tile*16;
    f32x4 acc[3];
    #pragma unroll
    for(int ct = 0; ct < 3; ct++) acc[ct] = (f32x4){0.f,0.f,0.f,0.f};
    #pragma unroll
    for(int kb = 0; kb < 4; kb++){
      short8 a = *reinterpret_cast<const short8*>(h + (size_t)(row0 + r_in)*HID + kb*32 + kg*8);
      #pragma unroll
      for(int ct = 0; ct < 3; ct++){
        short8 bb = *reinterpret_cast<const short8*>(&wlds[((ct*4+kb)*64+lane)*8]);
        acc[ct] = __builtin_amdgcn_mfma_f32_16x16x32_bf16(a, bb, acc[ct], 0, 0, 0);
      }
    }
    #pragma unroll
    for(int i = 0; i < 4; i++){
      float v0 = acc[0][i] + bias_s[r_in];
      float v1 = acc[1][i] + bias_s[16 + r_in];
      float v2 = acc[2][i] + bias_s[32 + r_in];
      float m = fmaxf(fmaxf(v0, v1), v2);
      #pragma unroll
      for(int o = 8; o > 0; o >>= 1) m = fmaxf(m, __shfl_xor(m, o));
      float s = expf(v0 - m) + expf(v1 - m) + expf(v2 - m);
      #pragma unroll
      for(int o = 8; o > 0; o >>= 1) s += __shfl_xor(s, o);
      const float ls = m + logf(s);
      const int row = row0 + kg*4 + i;
      float* op = out + (size_t)row*NCLS;
      op[r_in] = v0 - ls;
      op[16 + r_in] = v1 - ls;
      if(r_in < 8) op[32 + r_in] = v2 - ls;
    }
  }
}

extern "C" void kernel_launch(void* const* d_in, const int* in_sizes, int n_in,
                              void* d_out, int out_size, void* d_ws, size_t ws_size,
                              hipStream_t stream)
{
  const float* x      = (const float*)d_in[0];
  const int*   ei     = (const int*)  d_in[1];
  const float* W_pre  = (const float*)d_in[2];
  const float* b_pre  = (const float*)d_in[3];
  const float* Wl0    = (const float*)d_in[4];
  const float* bl0    = (const float*)d_in[5];
  const float* Wr0    = (const float*)d_in[6];
  const float* Wl1    = (const float*)d_in[7];
  const float* bl1    = (const float*)d_in[8];
  const float* Wr1    = (const float*)d_in[9];
  const float* W_post = (const float*)d_in[10];
  const float* b_post = (const float*)d_in[11];
  float* out = (float*)d_out;

  const int E = in_sizes[1] / 2;
  const int* src = ei;
  const int* dst = ei + E;

  char* ws = (char*)d_ws;
  size_t off = 0;
  auto alloc = [&](size_t bytes)->void*{
    void* p = ws + off;
    off += (bytes + 255) & ~(size_t)255;
    return p;
  };
  unsigned short* hA = (unsigned short*)alloc((size_t)N_NODES*HID*2);
  unsigned short* hB = (unsigned short*)alloc((size_t)N_NODES*HID*2);
  unsigned short* hM = (unsigned short*)alloc((size_t)N_NODES*HID*2);
  int* pk     = (int*)alloc((size_t)E*4);
  int* cnt    = (int*)alloc((size_t)NC*NB*4);
  int* wbase  = (int*)alloc((size_t)NC*NB*4);
  int* btot   = (int*)alloc((size_t)NB*4);
  int* bstart = (int*)alloc((size_t)(NB+1)*4);
  unsigned short* wimg = (unsigned short*)alloc(104448*2);

  // ---- weight pre-pack ----
  k_wprep<<<51, 256, 0, stream>>>(W_pre, Wl0, Wr0, Wl1, Wr1, W_post, wimg);

  // ---- bucketed edge partition (448-way grid) ----
  k_hist<<<NC, 256, 0, stream>>>(dst, E, cnt);
  k_bscanA<<<NB, 256, 0, stream>>>(cnt, wbase, btot);
  k_bscanB<<<1, 1024, 0, stream>>>(btot, bstart, E);
  k_place<<<NC, 256, 0, stream>>>(src, dst, E, wbase, bstart, pk);

  // ---- pre linear ----
  k_gemm_pre<<<512, 256, 0, stream>>>(x, wimg, b_pre, hA);

  // ---- SAGE layer 0 ----
  k_agg_b<<<NB, 512, 0, stream>>>(hA, pk, bstart, hM);
  k_gemm_sage<<<1563, 256, 0, stream>>>(hM, hA, wimg + 32768, bl0, hB);

  // ---- SAGE layer 1 ----
  k_agg_b<<<NB, 512, 0, stream>>>(hB, pk, bstart, hM);
  k_gemm_sage<<<1563, 256, 0, stream>>>(hM, hB, wimg + 65536, bl1, hA);

  // ---- post linear + log_softmax ----
  k_post<<<1563, 256, 0, stream>>>(hA, wimg + 98304, b_post, out);
}